// Round 1
// baseline (510.464 us; speedup 1.0000x reference)
//
#include <hip/hip_runtime.h>

// ============================================================================
// MixerBlock: the reference's attention (QK^T softmax) is DEAD CODE — `heads`
// is V only; masks are discarded. Effective graph:
//   x1 = LN1(patches)
//   sa = x1 @ Wc^T + bc        where Wc = out_w @ Wv  (768x768, precomputed)
//   x2 = sa + x1               (stored fp32 in d_out, reused as scratch)
//   x3 = LN2(x2)
//   h  = selu(x3 @ w1^T + b1)
//   out= h @ w2^T + b2 + x3
// All GEMMs: bf16 MFMA 16x16x32, m97-style 128x128 tile, global_load_lds(16B).
// ============================================================================

typedef __bf16 bf16;
typedef __bf16 bf16x8 __attribute__((ext_vector_type(8)));
typedef __bf16 bf16x4 __attribute__((ext_vector_type(4)));
typedef float  f32x4  __attribute__((ext_vector_type(4)));

#define D_MODEL 768
#define N_ROWS  16384   // B*S = 8*2048

// ---------------------------------------------------------------------------
// fp32 -> bf16 cast, 4 elems/thread
__global__ __launch_bounds__(256) void cast_kernel(const float* __restrict__ x,
                                                   bf16* __restrict__ y, int n4) {
  int i = blockIdx.x * 256 + threadIdx.x;
  if (i >= n4) return;
  float4 v = ((const float4*)x)[i];
  bf16x4 o = {(bf16)v.x, (bf16)v.y, (bf16)v.z, (bf16)v.w};
  *(bf16x4*)(y + 4 * (size_t)i) = o;
}

// ---------------------------------------------------------------------------
// WvT[k][j] = in_weight[(j*3+2)*768 + k]   (Wv transposed, bf16)
// grid (3, 768), block 256: coalesced reads over k.
__global__ __launch_bounds__(256) void wvt_kernel(const float* __restrict__ in_weight,
                                                  bf16* __restrict__ wvt) {
  int k = blockIdx.x * 256 + threadIdx.x;  // 0..767
  int j = blockIdx.y;                      // 0..767
  wvt[(size_t)k * 768 + j] = (bf16)in_weight[((size_t)j * 3 + 2) * 768 + k];
}

// ---------------------------------------------------------------------------
// bc[n] = sum_j out_w[n,j] * in_bias[j*3+2] + out_b[n]   (fp32)
__global__ __launch_bounds__(64) void bias_combine_kernel(const float* __restrict__ out_w,
                                                          const float* __restrict__ in_bias,
                                                          const float* __restrict__ out_b,
                                                          float* __restrict__ bc) {
  int n = blockIdx.x, l = threadIdx.x;
  float s = 0.f;
  for (int j = l; j < 768; j += 64) s += out_w[(size_t)n * 768 + j] * in_bias[j * 3 + 2];
#pragma unroll
  for (int off = 32; off > 0; off >>= 1) s += __shfl_xor(s, off, 64);
  if (l == 0) bc[n] = s + out_b[n];
}

// ---------------------------------------------------------------------------
// LayerNorm: one row (768 fp32) per block of 256 threads, write bf16.
__global__ __launch_bounds__(256) void ln_kernel(const float* __restrict__ x,
                                                 const float* __restrict__ g,
                                                 const float* __restrict__ b,
                                                 bf16* __restrict__ y) {
  const int row = blockIdx.x;
  const float* xr = x + (size_t)row * 768;
  float v[3], s1 = 0.f, s2 = 0.f;
#pragma unroll
  for (int i = 0; i < 3; ++i) {
    v[i] = xr[threadIdx.x + i * 256];
    s1 += v[i];
    s2 += v[i] * v[i];
  }
#pragma unroll
  for (int off = 32; off > 0; off >>= 1) {
    s1 += __shfl_xor(s1, off, 64);
    s2 += __shfl_xor(s2, off, 64);
  }
  __shared__ float red[8];
  int w = threadIdx.x >> 6, l = threadIdx.x & 63;
  if (l == 0) { red[w * 2] = s1; red[w * 2 + 1] = s2; }
  __syncthreads();
  s1 = red[0] + red[2] + red[4] + red[6];
  s2 = red[1] + red[3] + red[5] + red[7];
  const float mu = s1 * (1.f / 768.f);
  const float var = s2 * (1.f / 768.f) - mu * mu;
  const float rstd = rsqrtf(var + 1e-5f);
#pragma unroll
  for (int i = 0; i < 3; ++i) {
    int d = threadIdx.x + i * 256;
    y[(size_t)row * 768 + d] = (bf16)((v[i] - mu) * rstd * g[d] + b[d]);
  }
}

// ---------------------------------------------------------------------------
// m97-style GEMM: C[M][N] = A[M][K] @ B[N][K]^T  (+ epilogue)
//   EPI 0: out bf16 = acc                      (weight-combine Wc)
//   EPI 1: out f32  = acc + bias[n] + resid    (proj+residual / mlp2+residual)
//   EPI 2: out bf16 = selu(acc + bias[n])      (mlp1)
// 128x128 tile, BK=32, 256 threads = 4 waves in 2x2, each wave 4x4 frags of
// 16x16x32. LDS tiles [128][32] bf16, unpadded (global_load_lds requirement;
// b128 frag reads hit the 8-phase LDS floor regardless — see session notes).
template <int EPI>
__global__ __launch_bounds__(256) void gemm_bt(const bf16* __restrict__ A,
                                               const bf16* __restrict__ B,
                                               const float* __restrict__ bias,
                                               const bf16* __restrict__ resid,
                                               void* __restrict__ out,
                                               int M, int N, int K) {
  __shared__ bf16 sA[128 * 32];
  __shared__ bf16 sB[128 * 32];
  const int tid = threadIdx.x;
  const int w = tid >> 6, l = tid & 63;
  const int wr = w >> 1, wc = w & 1;
  const int q = l >> 4, m16 = l & 15;
  const long tileM = (long)blockIdx.y * 128;
  const long tileN = (long)blockIdx.x * 128;

  f32x4 acc[4][4] = {};

  for (int k0 = 0; k0 < K; k0 += 32) {
    // stage A-tile and B-tile (8KB each): 16B per lane per issue,
    // LDS dest = wave-uniform base + lane*16 (contiguous chunk order).
#pragma unroll
    for (int i = 0; i < 2; ++i) {
      const int ch = tid + i * 256;          // chunk 0..511
      const int row = ch >> 2;               // 4 chunks per 64B row
      const int c8 = (ch & 3) * 8;
      const bf16* ga = A + (tileM + row) * (long)K + k0 + c8;
      const bf16* gb = B + (tileN + row) * (long)K + k0 + c8;
      __builtin_amdgcn_global_load_lds(
          (const __attribute__((address_space(1))) void*)ga,
          (__attribute__((address_space(3))) void*)(&sA[ch * 8]), 16, 0, 0);
      __builtin_amdgcn_global_load_lds(
          (const __attribute__((address_space(1))) void*)gb,
          (__attribute__((address_space(3))) void*)(&sB[ch * 8]), 16, 0, 0);
    }
    __syncthreads();  // vmcnt(0) drain: staging visible

    bf16x8 af[4], bfr[4];
#pragma unroll
    for (int mi = 0; mi < 4; ++mi)
      af[mi] = *(const bf16x8*)&sA[(wr * 64 + mi * 16 + m16) * 32 + q * 8];
#pragma unroll
    for (int ni = 0; ni < 4; ++ni)
      bfr[ni] = *(const bf16x8*)&sB[(wc * 64 + ni * 16 + m16) * 32 + q * 8];
#pragma unroll
    for (int mi = 0; mi < 4; ++mi)
#pragma unroll
      for (int ni = 0; ni < 4; ++ni)
        acc[mi][ni] = __builtin_amdgcn_mfma_f32_16x16x32_bf16(af[mi], bfr[ni],
                                                              acc[mi][ni], 0, 0, 0);
    __syncthreads();  // compute done before next overwrite
  }

  // epilogue: C/D layout col = lane&15, row = (lane>>4)*4 + reg  (m89-verified)
  const long colBase = tileN + wc * 64 + m16;
  const long rowBase = tileM + wr * 64 + q * 4;
#pragma unroll
  for (int mi = 0; mi < 4; ++mi) {
#pragma unroll
    for (int r = 0; r < 4; ++r) {
      const long row = rowBase + mi * 16 + r;
#pragma unroll
      for (int ni = 0; ni < 4; ++ni) {
        const long col = colBase + ni * 16;
        float v = acc[mi][ni][r];
        if (EPI == 0) {
          ((bf16*)out)[row * N + col] = (bf16)v;
        } else if (EPI == 1) {
          v += bias[col] + (float)resid[row * N + col];
          ((float*)out)[row * N + col] = v;
        } else {  // EPI == 2: selu
          v += bias[col];
          v = v > 0.f ? 1.0507009873554805f * v
                      : 1.0507009873554805f * 1.6732632423543772f * (__expf(v) - 1.f);
          ((bf16*)out)[row * N + col] = (bf16)v;
        }
      }
    }
  }
}

// ---------------------------------------------------------------------------
extern "C" void kernel_launch(void* const* d_in, const int* in_sizes, int n_in,
                              void* d_out, int out_size, void* d_ws, size_t ws_size,
                              hipStream_t stream) {
  const float* patches   = (const float*)d_in[0];
  const float* in_weight = (const float*)d_in[1];
  const float* in_bias   = (const float*)d_in[2];
  const float* out_w     = (const float*)d_in[3];
  const float* out_b     = (const float*)d_in[4];
  const float* mlp_w1    = (const float*)d_in[5];
  const float* mlp_b1    = (const float*)d_in[6];
  const float* mlp_w2    = (const float*)d_in[7];
  const float* mlp_b2    = (const float*)d_in[8];
  const float* ln1_g     = (const float*)d_in[9];
  const float* ln1_b     = (const float*)d_in[10];
  const float* ln2_g     = (const float*)d_in[11];
  const float* ln2_b     = (const float*)d_in[12];

  char* ws = (char*)d_ws;
  const size_t MB = 1024 * 1024;
  bf16* Wc   = (bf16*)(ws + 0);        // 1.2 MB  (combined out_w @ Wv, [n][k])
  bf16* w1b  = (bf16*)(ws + 2 * MB);   // 4.7 MB
  bf16* w2b  = (bf16*)(ws + 8 * MB);   // 4.7 MB
  bf16* owb  = (bf16*)(ws + 14 * MB);  // 1.2 MB
  bf16* wvt  = (bf16*)(ws + 16 * MB);  // 1.2 MB
  float* bc  = (float*)(ws + 18 * MB); // 3 KB
  bf16* X1   = (bf16*)(ws + 20 * MB);  // 25 MB  [live LN1 -> gemm1]
  bf16* X3   = (bf16*)(ws + 20 * MB);  // 25 MB  [reuses X1: live LN2 -> gemm3]
  bf16* H    = (bf16*)(ws + 48 * MB);  // 100 MB [live gemm2 -> gemm3]
  float* X2  = (float*)d_out;          // 50 MB fp32 scratch inside d_out

  // --- weight preprocessing (every call; no static guards) ---
  cast_kernel<<<(3072 * 768 / 4 + 255) / 256, 256, 0, stream>>>(mlp_w1, w1b, 3072 * 768 / 4);
  cast_kernel<<<(768 * 3072 / 4 + 255) / 256, 256, 0, stream>>>(mlp_w2, w2b, 768 * 3072 / 4);
  cast_kernel<<<(768 * 768 / 4 + 255) / 256, 256, 0, stream>>>(out_w, owb, 768 * 768 / 4);
  wvt_kernel<<<dim3(3, 768), 256, 0, stream>>>(in_weight, wvt);
  bias_combine_kernel<<<768, 64, 0, stream>>>(out_w, in_bias, out_b, bc);
  // Wc[n][k] = sum_j out_w[n][j] * WvT[k][j]  -> gemm with A=owb, B=wvt
  gemm_bt<0><<<dim3(6, 6), 256, 0, stream>>>(owb, wvt, nullptr, nullptr, Wc, 768, 768, 768);

  // --- main pipeline ---
  ln_kernel<<<N_ROWS, 256, 0, stream>>>(patches, ln1_g, ln1_b, X1);
  // x2 = x1 @ Wc^T + bc + x1   (fp32, into d_out scratch)
  gemm_bt<1><<<dim3(6, 128), 256, 0, stream>>>(X1, Wc, bc, X1, X2, N_ROWS, 768, 768);
  ln_kernel<<<N_ROWS, 256, 0, stream>>>(X2, ln2_g, ln2_b, X3);
  // h = selu(x3 @ w1^T + b1)
  gemm_bt<2><<<dim3(24, 128), 256, 0, stream>>>(X3, w1b, mlp_b1, nullptr, H, N_ROWS, 3072, 768);
  // out = h @ w2^T + b2 + x3   (fp32 final, overwrites X2 region of d_out)
  gemm_bt<1><<<dim3(6, 128), 256, 0, stream>>>(H, w2b, mlp_b2, X3, d_out, N_ROWS, 768, 3072);
}

// Round 2
// 476.233 us; speedup vs baseline: 1.0719x; 1.0719x over previous
//
#include <hip/hip_runtime.h>

// ============================================================================
// MixerBlock (attention QK^T/softmax is dead code; heads = V only):
//   x1 = LN1(patches); sa = x1 @ Wc^T + bc  (Wc = out_w @ Wv, precomputed)
//   x2 = sa + x1 (fp32, in d_out); x3 = LN2(x2)
//   h = selu(x3 @ w1^T + b1); out = h @ w2^T + b2 + x3
// R2 changes vs R1:
//   - XCD-aware block remap in gemm_bt: each XCD owns gridy/8 m-strips,
//     m-fastest within XCD -> A strips stay L2-resident across all n-tiles.
//   - LDS chunk swizzle (stored col = (c_log + row>>1) & 3): frag ds_read_b128
//     hits all 8 bank groups 2x per quad -> 2-way (free) instead of 8-way.
// ============================================================================

typedef __bf16 bf16;
typedef __bf16 bf16x8 __attribute__((ext_vector_type(8)));
typedef __bf16 bf16x4 __attribute__((ext_vector_type(4)));
typedef float  f32x4  __attribute__((ext_vector_type(4)));

#define N_ROWS  16384   // B*S = 8*2048

// ---------------------------------------------------------------------------
__global__ __launch_bounds__(256) void cast_kernel(const float* __restrict__ x,
                                                   bf16* __restrict__ y, int n4) {
  int i = blockIdx.x * 256 + threadIdx.x;
  if (i >= n4) return;
  float4 v = ((const float4*)x)[i];
  bf16x4 o = {(bf16)v.x, (bf16)v.y, (bf16)v.z, (bf16)v.w};
  *(bf16x4*)(y + 4 * (size_t)i) = o;
}

// ---------------------------------------------------------------------------
// WvT[k][j] = in_weight[(j*3+2)*768 + k]
__global__ __launch_bounds__(256) void wvt_kernel(const float* __restrict__ in_weight,
                                                  bf16* __restrict__ wvt) {
  int k = blockIdx.x * 256 + threadIdx.x;
  int j = blockIdx.y;
  wvt[(size_t)k * 768 + j] = (bf16)in_weight[((size_t)j * 3 + 2) * 768 + k];
}

// ---------------------------------------------------------------------------
__global__ __launch_bounds__(64) void bias_combine_kernel(const float* __restrict__ out_w,
                                                          const float* __restrict__ in_bias,
                                                          const float* __restrict__ out_b,
                                                          float* __restrict__ bc) {
  int n = blockIdx.x, l = threadIdx.x;
  float s = 0.f;
  for (int j = l; j < 768; j += 64) s += out_w[(size_t)n * 768 + j] * in_bias[j * 3 + 2];
#pragma unroll
  for (int off = 32; off > 0; off >>= 1) s += __shfl_xor(s, off, 64);
  if (l == 0) bc[n] = s + out_b[n];
}

// ---------------------------------------------------------------------------
__global__ __launch_bounds__(256) void ln_kernel(const float* __restrict__ x,
                                                 const float* __restrict__ g,
                                                 const float* __restrict__ b,
                                                 bf16* __restrict__ y) {
  const int row = blockIdx.x;
  const float* xr = x + (size_t)row * 768;
  float v[3], s1 = 0.f, s2 = 0.f;
#pragma unroll
  for (int i = 0; i < 3; ++i) {
    v[i] = xr[threadIdx.x + i * 256];
    s1 += v[i];
    s2 += v[i] * v[i];
  }
#pragma unroll
  for (int off = 32; off > 0; off >>= 1) {
    s1 += __shfl_xor(s1, off, 64);
    s2 += __shfl_xor(s2, off, 64);
  }
  __shared__ float red[8];
  int w = threadIdx.x >> 6, l = threadIdx.x & 63;
  if (l == 0) { red[w * 2] = s1; red[w * 2 + 1] = s2; }
  __syncthreads();
  s1 = red[0] + red[2] + red[4] + red[6];
  s2 = red[1] + red[3] + red[5] + red[7];
  const float mu = s1 * (1.f / 768.f);
  const float var = s2 * (1.f / 768.f) - mu * mu;
  const float rstd = rsqrtf(var + 1e-5f);
#pragma unroll
  for (int i = 0; i < 3; ++i) {
    int d = threadIdx.x + i * 256;
    y[(size_t)row * 768 + d] = (bf16)((v[i] - mu) * rstd * g[d] + b[d]);
  }
}

// ---------------------------------------------------------------------------
// C[M][N] = A[M][K] @ B[N][K]^T (+ epilogue). 128x128 tile, BK=32, 4 waves.
// EPI 0: bf16 = acc | EPI 1: f32 = acc + bias[n] + resid | EPI 2: bf16 = selu
template <int EPI>
__global__ __launch_bounds__(256) void gemm_bt(const bf16* __restrict__ A,
                                               const bf16* __restrict__ B,
                                               const float* __restrict__ bias,
                                               const bf16* __restrict__ resid,
                                               void* __restrict__ out,
                                               int M, int N, int K) {
  __shared__ bf16 sA[128 * 32];
  __shared__ bf16 sB[128 * 32];
  const int tid = threadIdx.x;
  const int w = tid >> 6, l = tid & 63;
  const int wr = w >> 1, wc = w & 1;
  const int q = l >> 4, m16 = l & 15;

  // XCD-aware remap: XCD = linear%8 (round-robin heuristic). Give each XCD a
  // contiguous band of gridy/8 m-strips, iterate m fastest -> A band (16
  // strips) stays L2-resident across all n-tiles; B streams once per XCD.
  int mtile, ntile;
  {
    const int L = blockIdx.y * gridDim.x + blockIdx.x;
    const int gy = gridDim.y;
    if ((gy & 7) == 0) {
      const int mpx = gy >> 3;
      const int xcd = L & 7;
      const int slot = L >> 3;
      mtile = xcd * mpx + (slot % mpx);
      ntile = slot / mpx;
    } else {
      mtile = blockIdx.y; ntile = blockIdx.x;
    }
  }
  const long tileM = (long)mtile * 128;
  const long tileN = (long)ntile * 128;

  f32x4 acc[4][4] = {};

  for (int k0 = 0; k0 < K; k0 += 32) {
    // Stage 8KB per tile. LDS side stays linear (global_load_lds needs
    // wave-uniform base + lane*16); the SWIZZLE lives in which global chunk
    // each lane fetches: stored col (ch&3) holds logical col ((ch&3)-(row>>1))&3.
#pragma unroll
    for (int i = 0; i < 2; ++i) {
      const int ch = tid + i * 256;
      const int row = ch >> 2;
      const int clog = ((ch & 3) - (row >> 1)) & 3;
      const bf16* ga = A + (tileM + row) * (long)K + k0 + clog * 8;
      const bf16* gb = B + (tileN + row) * (long)K + k0 + clog * 8;
      __builtin_amdgcn_global_load_lds(
          (const __attribute__((address_space(1))) void*)ga,
          (__attribute__((address_space(3))) void*)(&sA[ch * 8]), 16, 0, 0);
      __builtin_amdgcn_global_load_lds(
          (const __attribute__((address_space(1))) void*)gb,
          (__attribute__((address_space(3))) void*)(&sB[ch * 8]), 16, 0, 0);
    }
    __syncthreads();

    // Frag reads: logical (row, q) lives at bf16 index row*32 + ((q+(row>>1))&3)*8.
    bf16x8 af[4], bfr[4];
#pragma unroll
    for (int mi = 0; mi < 4; ++mi) {
      const int r = wr * 64 + mi * 16 + m16;
      af[mi] = *(const bf16x8*)&sA[r * 32 + (((q + (r >> 1)) & 3) << 3)];
    }
#pragma unroll
    for (int ni = 0; ni < 4; ++ni) {
      const int r = wc * 64 + ni * 16 + m16;
      bfr[ni] = *(const bf16x8*)&sB[r * 32 + (((q + (r >> 1)) & 3) << 3)];
    }
#pragma unroll
    for (int mi = 0; mi < 4; ++mi)
#pragma unroll
      for (int ni = 0; ni < 4; ++ni)
        acc[mi][ni] = __builtin_amdgcn_mfma_f32_16x16x32_bf16(af[mi], bfr[ni],
                                                              acc[mi][ni], 0, 0, 0);
    __syncthreads();
  }

  // epilogue: C/D layout col = lane&15, row = (lane>>4)*4 + reg (m89-verified)
  const long colBase = tileN + wc * 64 + m16;
  const long rowBase = tileM + wr * 64 + q * 4;
#pragma unroll
  for (int mi = 0; mi < 4; ++mi) {
#pragma unroll
    for (int r = 0; r < 4; ++r) {
      const long row = rowBase + mi * 16 + r;
#pragma unroll
      for (int ni = 0; ni < 4; ++ni) {
        const long col = colBase + ni * 16;
        float v = acc[mi][ni][r];
        if (EPI == 0) {
          ((bf16*)out)[row * N + col] = (bf16)v;
        } else if (EPI == 1) {
          v += bias[col] + (float)resid[row * N + col];
          ((float*)out)[row * N + col] = v;
        } else {
          v += bias[col];
          v = v > 0.f ? 1.0507009873554805f * v
                      : 1.0507009873554805f * 1.6732632423543772f * (__expf(v) - 1.f);
          ((bf16*)out)[row * N + col] = (bf16)v;
        }
      }
    }
  }
}

// ---------------------------------------------------------------------------
extern "C" void kernel_launch(void* const* d_in, const int* in_sizes, int n_in,
                              void* d_out, int out_size, void* d_ws, size_t ws_size,
                              hipStream_t stream) {
  const float* patches   = (const float*)d_in[0];
  const float* in_weight = (const float*)d_in[1];
  const float* in_bias   = (const float*)d_in[2];
  const float* out_w     = (const float*)d_in[3];
  const float* out_b     = (const float*)d_in[4];
  const float* mlp_w1    = (const float*)d_in[5];
  const float* mlp_b1    = (const float*)d_in[6];
  const float* mlp_w2    = (const float*)d_in[7];
  const float* mlp_b2    = (const float*)d_in[8];
  const float* ln1_g     = (const float*)d_in[9];
  const float* ln1_b     = (const float*)d_in[10];
  const float* ln2_g     = (const float*)d_in[11];
  const float* ln2_b     = (const float*)d_in[12];

  char* ws = (char*)d_ws;
  const size_t MB = 1024 * 1024;
  bf16* Wc   = (bf16*)(ws + 0);
  bf16* w1b  = (bf16*)(ws + 2 * MB);
  bf16* w2b  = (bf16*)(ws + 8 * MB);
  bf16* owb  = (bf16*)(ws + 14 * MB);
  bf16* wvt  = (bf16*)(ws + 16 * MB);
  float* bc  = (float*)(ws + 18 * MB);
  bf16* X1   = (bf16*)(ws + 20 * MB);  // reused as X3
  bf16* X3   = (bf16*)(ws + 20 * MB);
  bf16* H    = (bf16*)(ws + 48 * MB);
  float* X2  = (float*)d_out;          // fp32 scratch inside d_out

  cast_kernel<<<(3072 * 768 / 4 + 255) / 256, 256, 0, stream>>>(mlp_w1, w1b, 3072 * 768 / 4);
  cast_kernel<<<(768 * 3072 / 4 + 255) / 256, 256, 0, stream>>>(mlp_w2, w2b, 768 * 3072 / 4);
  cast_kernel<<<(768 * 768 / 4 + 255) / 256, 256, 0, stream>>>(out_w, owb, 768 * 768 / 4);
  wvt_kernel<<<dim3(3, 768), 256, 0, stream>>>(in_weight, wvt);
  bias_combine_kernel<<<768, 64, 0, stream>>>(out_w, in_bias, out_b, bc);
  gemm_bt<0><<<dim3(6, 6), 256, 0, stream>>>(owb, wvt, nullptr, nullptr, Wc, 768, 768, 768);

  ln_kernel<<<N_ROWS, 256, 0, stream>>>(patches, ln1_g, ln1_b, X1);
  gemm_bt<1><<<dim3(6, 128), 256, 0, stream>>>(X1, Wc, bc, X1, X2, N_ROWS, 768, 768);
  ln_kernel<<<N_ROWS, 256, 0, stream>>>(X2, ln2_g, ln2_b, X3);
  gemm_bt<2><<<dim3(24, 128), 256, 0, stream>>>(X3, w1b, mlp_b1, nullptr, H, N_ROWS, 3072, 768);
  gemm_bt<1><<<dim3(6, 128), 256, 0, stream>>>(H, w2b, mlp_b2, X3, d_out, N_ROWS, 768, 3072);
}

// Round 3
// 426.810 us; speedup vs baseline: 1.1960x; 1.1158x over previous
//
#include <hip/hip_runtime.h>

// ============================================================================
// MixerBlock (attention QK^T/softmax is dead code; heads = V only):
//   x1 = LN1(patches); sa = x1 @ Wc^T + bc  (Wc = out_w @ Wv, precomputed)
//   x2 = sa + x1 (fp32, in d_out); x3 = LN2(x2)
//   h = selu(x3 @ w1^T + b1); out = h @ w2^T + b2 + x3
// R3 changes vs R2:
//   - Double-buffered LDS + prefetch-before-compute K-loop: stage tile k+1,
//     then compute tile k, then ONE barrier (was 2). Staging latency hidden
//     behind MFMA+ds_read instead of fully exposed at vmcnt(0) drain.
//   - All staging pointers & frag LDS offsets hoisted out of the K-loop
//     (R2 recomputed swizzle arithmetic every iteration -> 31% VALUBusy).
// Kept from R2: XCD-aware m-band remap (FETCH at ideal floor), LDS chunk
// swizzle (0 bank conflicts).
// ============================================================================

typedef __bf16 bf16;
typedef __bf16 bf16x8 __attribute__((ext_vector_type(8)));
typedef __bf16 bf16x4 __attribute__((ext_vector_type(4)));
typedef float  f32x4  __attribute__((ext_vector_type(4)));

#define N_ROWS  16384   // B*S = 8*2048

#define AS1(p) ((const __attribute__((address_space(1))) void*)(p))
#define AS3(p) ((__attribute__((address_space(3))) void*)(p))

// ---------------------------------------------------------------------------
__global__ __launch_bounds__(256) void cast_kernel(const float* __restrict__ x,
                                                   bf16* __restrict__ y, int n4) {
  int i = blockIdx.x * 256 + threadIdx.x;
  if (i >= n4) return;
  float4 v = ((const float4*)x)[i];
  bf16x4 o = {(bf16)v.x, (bf16)v.y, (bf16)v.z, (bf16)v.w};
  *(bf16x4*)(y + 4 * (size_t)i) = o;
}

// ---------------------------------------------------------------------------
// WvT[k][j] = in_weight[(j*3+2)*768 + k]
__global__ __launch_bounds__(256) void wvt_kernel(const float* __restrict__ in_weight,
                                                  bf16* __restrict__ wvt) {
  int k = blockIdx.x * 256 + threadIdx.x;
  int j = blockIdx.y;
  wvt[(size_t)k * 768 + j] = (bf16)in_weight[((size_t)j * 3 + 2) * 768 + k];
}

// ---------------------------------------------------------------------------
__global__ __launch_bounds__(64) void bias_combine_kernel(const float* __restrict__ out_w,
                                                          const float* __restrict__ in_bias,
                                                          const float* __restrict__ out_b,
                                                          float* __restrict__ bc) {
  int n = blockIdx.x, l = threadIdx.x;
  float s = 0.f;
  for (int j = l; j < 768; j += 64) s += out_w[(size_t)n * 768 + j] * in_bias[j * 3 + 2];
#pragma unroll
  for (int off = 32; off > 0; off >>= 1) s += __shfl_xor(s, off, 64);
  if (l == 0) bc[n] = s + out_b[n];
}

// ---------------------------------------------------------------------------
__global__ __launch_bounds__(256) void ln_kernel(const float* __restrict__ x,
                                                 const float* __restrict__ g,
                                                 const float* __restrict__ b,
                                                 bf16* __restrict__ y) {
  const int row = blockIdx.x;
  const float* xr = x + (size_t)row * 768;
  float v[3], s1 = 0.f, s2 = 0.f;
#pragma unroll
  for (int i = 0; i < 3; ++i) {
    v[i] = xr[threadIdx.x + i * 256];
    s1 += v[i];
    s2 += v[i] * v[i];
  }
#pragma unroll
  for (int off = 32; off > 0; off >>= 1) {
    s1 += __shfl_xor(s1, off, 64);
    s2 += __shfl_xor(s2, off, 64);
  }
  __shared__ float red[8];
  int w = threadIdx.x >> 6, l = threadIdx.x & 63;
  if (l == 0) { red[w * 2] = s1; red[w * 2 + 1] = s2; }
  __syncthreads();
  s1 = red[0] + red[2] + red[4] + red[6];
  s2 = red[1] + red[3] + red[5] + red[7];
  const float mu = s1 * (1.f / 768.f);
  const float var = s2 * (1.f / 768.f) - mu * mu;
  const float rstd = rsqrtf(var + 1e-5f);
#pragma unroll
  for (int i = 0; i < 3; ++i) {
    int d = threadIdx.x + i * 256;
    y[(size_t)row * 768 + d] = (bf16)((v[i] - mu) * rstd * g[d] + b[d]);
  }
}

// ---------------------------------------------------------------------------
// C[M][N] = A[M][K] @ B[N][K]^T (+ epilogue). 128x128 tile, BK=32, 4 waves,
// double-buffered LDS, single barrier per K-iter.
// EPI 0: bf16 = acc | EPI 1: f32 = acc + bias[n] + resid | EPI 2: bf16 = selu
template <int EPI>
__global__ __launch_bounds__(256) void gemm_bt(const bf16* __restrict__ A,
                                               const bf16* __restrict__ B,
                                               const float* __restrict__ bias,
                                               const bf16* __restrict__ resid,
                                               void* __restrict__ out,
                                               int M, int N, int K) {
  __shared__ bf16 sA0[128 * 32], sA1[128 * 32];
  __shared__ bf16 sB0[128 * 32], sB1[128 * 32];
  const int tid = threadIdx.x;
  const int w = tid >> 6, l = tid & 63;
  const int wr = w >> 1, wc = w & 1;
  const int q = l >> 4, m16 = l & 15;

  // XCD-aware remap (XCD = linear%8): each XCD owns a contiguous band of
  // gridy/8 m-strips, m fastest -> A band L2-resident across n-tiles.
  int mtile, ntile;
  {
    const int L = blockIdx.y * gridDim.x + blockIdx.x;
    const int gy = gridDim.y;
    if ((gy & 7) == 0) {
      const int mpx = gy >> 3;
      const int xcd = L & 7;
      const int slot = L >> 3;
      mtile = xcd * mpx + (slot % mpx);
      ntile = slot / mpx;
    } else {
      mtile = blockIdx.y; ntile = blockIdx.x;
    }
  }
  const long tileM = (long)mtile * 128;
  const long tileN = (long)ntile * 128;

  // --- hoisted staging geometry (chunk swizzle: stored col (ch&3) holds
  // logical col ((ch&3)-(row>>1))&3 -> frag ds_read_b128 is conflict-free) ---
  const int ch0 = tid, ch1 = tid + 256;
  const int row0 = ch0 >> 2, row1 = ch1 >> 2;
  const int cl0 = ((ch0 & 3) - (row0 >> 1)) & 3;
  const int cl1 = ((ch1 & 3) - (row1 >> 1)) & 3;
  const bf16* ga0 = A + (tileM + row0) * (long)K + cl0 * 8;
  const bf16* ga1 = A + (tileM + row1) * (long)K + cl1 * 8;
  const bf16* gb0 = B + (tileN + row0) * (long)K + cl0 * 8;
  const bf16* gb1 = B + (tileN + row1) * (long)K + cl1 * 8;
  const int ld0 = ch0 * 8, ld1 = ch1 * 8;

  // --- hoisted fragment LDS offsets (logical (r,q) at r*32+((q+(r>>1))&3)*8)
  int offA[4], offB[4];
#pragma unroll
  for (int mi = 0; mi < 4; ++mi) {
    const int r = wr * 64 + mi * 16 + m16;
    offA[mi] = r * 32 + (((q + (r >> 1)) & 3) << 3);
  }
#pragma unroll
  for (int ni = 0; ni < 4; ++ni) {
    const int r = wc * 64 + ni * 16 + m16;
    offB[ni] = r * 32 + (((q + (r >> 1)) & 3) << 3);
  }

  f32x4 acc[4][4] = {};

  // stage tile 0 into buf0
  __builtin_amdgcn_global_load_lds(AS1(ga0), AS3(&sA0[ld0]), 16, 0, 0);
  __builtin_amdgcn_global_load_lds(AS1(ga1), AS3(&sA0[ld1]), 16, 0, 0);
  __builtin_amdgcn_global_load_lds(AS1(gb0), AS3(&sB0[ld0]), 16, 0, 0);
  __builtin_amdgcn_global_load_lds(AS1(gb1), AS3(&sB0[ld1]), 16, 0, 0);
  __syncthreads();

  const bf16 *cra = sA0, *crb = sB0;
  bf16 *nxa = sA1, *nxb = sB1;

#pragma unroll 2
  for (long k0 = 32; k0 < K; k0 += 32) {
    // prefetch tile k0 into the other buffer (no wait here)
    __builtin_amdgcn_global_load_lds(AS1(ga0 + k0), AS3(&nxa[ld0]), 16, 0, 0);
    __builtin_amdgcn_global_load_lds(AS1(ga1 + k0), AS3(&nxa[ld1]), 16, 0, 0);
    __builtin_amdgcn_global_load_lds(AS1(gb0 + k0), AS3(&nxb[ld0]), 16, 0, 0);
    __builtin_amdgcn_global_load_lds(AS1(gb1 + k0), AS3(&nxb[ld1]), 16, 0, 0);

    // compute current tile
    bf16x8 af[4], bfr[4];
#pragma unroll
    for (int mi = 0; mi < 4; ++mi) af[mi] = *(const bf16x8*)&cra[offA[mi]];
#pragma unroll
    for (int ni = 0; ni < 4; ++ni) bfr[ni] = *(const bf16x8*)&crb[offB[ni]];
#pragma unroll
    for (int mi = 0; mi < 4; ++mi)
#pragma unroll
      for (int ni = 0; ni < 4; ++ni)
        acc[mi][ni] = __builtin_amdgcn_mfma_f32_16x16x32_bf16(af[mi], bfr[ni],
                                                              acc[mi][ni], 0, 0, 0);

    __syncthreads();  // drains prefetch (vmcnt) after it had compute-time to land

    const bf16* ta = cra; cra = nxa; nxa = (bf16*)ta;
    const bf16* tb = crb; crb = nxb; nxb = (bf16*)tb;
  }

  // last tile
  {
    bf16x8 af[4], bfr[4];
#pragma unroll
    for (int mi = 0; mi < 4; ++mi) af[mi] = *(const bf16x8*)&cra[offA[mi]];
#pragma unroll
    for (int ni = 0; ni < 4; ++ni) bfr[ni] = *(const bf16x8*)&crb[offB[ni]];
#pragma unroll
    for (int mi = 0; mi < 4; ++mi)
#pragma unroll
      for (int ni = 0; ni < 4; ++ni)
        acc[mi][ni] = __builtin_amdgcn_mfma_f32_16x16x32_bf16(af[mi], bfr[ni],
                                                              acc[mi][ni], 0, 0, 0);
  }

  // epilogue: C/D layout col = lane&15, row = (lane>>4)*4 + reg (m89-verified)
  const long colBase = tileN + wc * 64 + m16;
  const long rowBase = tileM + wr * 64 + q * 4;
#pragma unroll
  for (int mi = 0; mi < 4; ++mi) {
#pragma unroll
    for (int r = 0; r < 4; ++r) {
      const long row = rowBase + mi * 16 + r;
#pragma unroll
      for (int ni = 0; ni < 4; ++ni) {
        const long col = colBase + ni * 16;
        float v = acc[mi][ni][r];
        if (EPI == 0) {
          ((bf16*)out)[row * N + col] = (bf16)v;
        } else if (EPI == 1) {
          v += bias[col] + (float)resid[row * N + col];
          ((float*)out)[row * N + col] = v;
        } else {
          v += bias[col];
          v = v > 0.f ? 1.0507009873554805f * v
                      : 1.0507009873554805f * 1.6732632423543772f * (__expf(v) - 1.f);
          ((bf16*)out)[row * N + col] = (bf16)v;
        }
      }
    }
  }
}

// ---------------------------------------------------------------------------
extern "C" void kernel_launch(void* const* d_in, const int* in_sizes, int n_in,
                              void* d_out, int out_size, void* d_ws, size_t ws_size,
                              hipStream_t stream) {
  const float* patches   = (const float*)d_in[0];
  const float* in_weight = (const float*)d_in[1];
  const float* in_bias   = (const float*)d_in[2];
  const float* out_w     = (const float*)d_in[3];
  const float* out_b     = (const float*)d_in[4];
  const float* mlp_w1    = (const float*)d_in[5];
  const float* mlp_b1    = (const float*)d_in[6];
  const float* mlp_w2    = (const float*)d_in[7];
  const float* mlp_b2    = (const float*)d_in[8];
  const float* ln1_g     = (const float*)d_in[9];
  const float* ln1_b     = (const float*)d_in[10];
  const float* ln2_g     = (const float*)d_in[11];
  const float* ln2_b     = (const float*)d_in[12];

  char* ws = (char*)d_ws;
  const size_t MB = 1024 * 1024;
  bf16* Wc   = (bf16*)(ws + 0);
  bf16* w1b  = (bf16*)(ws + 2 * MB);
  bf16* w2b  = (bf16*)(ws + 8 * MB);
  bf16* owb  = (bf16*)(ws + 14 * MB);
  bf16* wvt  = (bf16*)(ws + 16 * MB);
  float* bc  = (float*)(ws + 18 * MB);
  bf16* X1   = (bf16*)(ws + 20 * MB);  // reused as X3
  bf16* X3   = (bf16*)(ws + 20 * MB);
  bf16* H    = (bf16*)(ws + 48 * MB);
  float* X2  = (float*)d_out;          // fp32 scratch inside d_out

  cast_kernel<<<(3072 * 768 / 4 + 255) / 256, 256, 0, stream>>>(mlp_w1, w1b, 3072 * 768 / 4);
  cast_kernel<<<(768 * 3072 / 4 + 255) / 256, 256, 0, stream>>>(mlp_w2, w2b, 768 * 3072 / 4);
  cast_kernel<<<(768 * 768 / 4 + 255) / 256, 256, 0, stream>>>(out_w, owb, 768 * 768 / 4);
  wvt_kernel<<<dim3(3, 768), 256, 0, stream>>>(in_weight, wvt);
  bias_combine_kernel<<<768, 64, 0, stream>>>(out_w, in_bias, out_b, bc);
  gemm_bt<0><<<dim3(6, 6), 256, 0, stream>>>(owb, wvt, nullptr, nullptr, Wc, 768, 768, 768);

  ln_kernel<<<N_ROWS, 256, 0, stream>>>(patches, ln1_g, ln1_b, X1);
  gemm_bt<1><<<dim3(6, 128), 256, 0, stream>>>(X1, Wc, bc, X1, X2, N_ROWS, 768, 768);
  ln_kernel<<<N_ROWS, 256, 0, stream>>>(X2, ln2_g, ln2_b, X3);
  gemm_bt<2><<<dim3(24, 128), 256, 0, stream>>>(X3, w1b, mlp_b1, nullptr, H, N_ROWS, 3072, 768);
  gemm_bt<1><<<dim3(6, 128), 256, 0, stream>>>(H, w2b, mlp_b2, X3, d_out, N_ROWS, 768, 3072);
}

// Round 4
// 409.158 us; speedup vs baseline: 1.2476x; 1.0431x over previous
//
#include <hip/hip_runtime.h>

// ============================================================================
// MixerBlock (attention QK^T/softmax is dead code; heads = V only):
//   x1 = LN1(patches); sa = x1 @ Wc^T + bc  (Wc = out_w @ Wv, precomputed)
//   x2 = sa + x1 (fp32, in d_out); x3 = LN2(x2)
//   h = selu(x3 @ w1^T + b1); out = h @ w2^T + b2 + x3
// R4 change vs R3: wave tile 64x64 -> 128x64 (block tile 128x256, 4 waves
// tiling N). Arithmetic intensity per LDS byte: 16 -> 42.7 FLOP/B, lifting
// the LDS-BW ceiling from ~30% to ~80% of MFMA peak (R3 measured 29% = the
// 64x64 LDS-feed bound). acc = 8x4 f32x4 (128 AGPR), 2 waves/SIMD.
// Kept: 16x16x32 MFMA, chunk swizzle (0 bank conflicts), double-buffer +
// single barrier, XCD m-band remap (FETCH at floor).
// ============================================================================

typedef __bf16 bf16;
typedef __bf16 bf16x8 __attribute__((ext_vector_type(8)));
typedef __bf16 bf16x4 __attribute__((ext_vector_type(4)));
typedef float  f32x4  __attribute__((ext_vector_type(4)));

#define N_ROWS  16384   // B*S = 8*2048

#define AS1(p) ((const __attribute__((address_space(1))) void*)(p))
#define AS3(p) ((__attribute__((address_space(3))) void*)(p))

// ---------------------------------------------------------------------------
__global__ __launch_bounds__(256) void cast_kernel(const float* __restrict__ x,
                                                   bf16* __restrict__ y, int n4) {
  int i = blockIdx.x * 256 + threadIdx.x;
  if (i >= n4) return;
  float4 v = ((const float4*)x)[i];
  bf16x4 o = {(bf16)v.x, (bf16)v.y, (bf16)v.z, (bf16)v.w};
  *(bf16x4*)(y + 4 * (size_t)i) = o;
}

// ---------------------------------------------------------------------------
// WvT[k][j] = in_weight[(j*3+2)*768 + k]
__global__ __launch_bounds__(256) void wvt_kernel(const float* __restrict__ in_weight,
                                                  bf16* __restrict__ wvt) {
  int k = blockIdx.x * 256 + threadIdx.x;
  int j = blockIdx.y;
  wvt[(size_t)k * 768 + j] = (bf16)in_weight[((size_t)j * 3 + 2) * 768 + k];
}

// ---------------------------------------------------------------------------
__global__ __launch_bounds__(64) void bias_combine_kernel(const float* __restrict__ out_w,
                                                          const float* __restrict__ in_bias,
                                                          const float* __restrict__ out_b,
                                                          float* __restrict__ bc) {
  int n = blockIdx.x, l = threadIdx.x;
  float s = 0.f;
  for (int j = l; j < 768; j += 64) s += out_w[(size_t)n * 768 + j] * in_bias[j * 3 + 2];
#pragma unroll
  for (int off = 32; off > 0; off >>= 1) s += __shfl_xor(s, off, 64);
  if (l == 0) bc[n] = s + out_b[n];
}

// ---------------------------------------------------------------------------
__global__ __launch_bounds__(256) void ln_kernel(const float* __restrict__ x,
                                                 const float* __restrict__ g,
                                                 const float* __restrict__ b,
                                                 bf16* __restrict__ y) {
  const int row = blockIdx.x;
  const float* xr = x + (size_t)row * 768;
  float v[3], s1 = 0.f, s2 = 0.f;
#pragma unroll
  for (int i = 0; i < 3; ++i) {
    v[i] = xr[threadIdx.x + i * 256];
    s1 += v[i];
    s2 += v[i] * v[i];
  }
#pragma unroll
  for (int off = 32; off > 0; off >>= 1) {
    s1 += __shfl_xor(s1, off, 64);
    s2 += __shfl_xor(s2, off, 64);
  }
  __shared__ float red[8];
  int w = threadIdx.x >> 6, l = threadIdx.x & 63;
  if (l == 0) { red[w * 2] = s1; red[w * 2 + 1] = s2; }
  __syncthreads();
  s1 = red[0] + red[2] + red[4] + red[6];
  s2 = red[1] + red[3] + red[5] + red[7];
  const float mu = s1 * (1.f / 768.f);
  const float var = s2 * (1.f / 768.f) - mu * mu;
  const float rstd = rsqrtf(var + 1e-5f);
#pragma unroll
  for (int i = 0; i < 3; ++i) {
    int d = threadIdx.x + i * 256;
    y[(size_t)row * 768 + d] = (bf16)((v[i] - mu) * rstd * g[d] + b[d]);
  }
}

// ---------------------------------------------------------------------------
// C[M][N] = A[M][K] @ B[N][K]^T (+ epilogue). Block tile 128x256, BK=32,
// 4 waves each owning a 128x64 wave tile (8x4 frags of 16x16x32).
// Double-buffered LDS, single barrier per K-iter.
// EPI 0: bf16 = acc | EPI 1: f32 = acc + bias[n] + resid | EPI 2: bf16 = selu
template <int EPI>
__global__ __launch_bounds__(256, 2) void gemm_bt(const bf16* __restrict__ A,
                                                  const bf16* __restrict__ B,
                                                  const float* __restrict__ bias,
                                                  const bf16* __restrict__ resid,
                                                  void* __restrict__ out,
                                                  int M, int N, int K) {
  __shared__ bf16 sA0[128 * 32], sA1[128 * 32];   // 8 KB each
  __shared__ bf16 sB0[256 * 32], sB1[256 * 32];   // 16 KB each
  const int tid = threadIdx.x;
  const int w = tid >> 6, l = tid & 63;
  const int q = l >> 4, m16 = l & 15;

  // XCD-aware remap (XCD = linear%8): each XCD owns a contiguous band of
  // gridy/8 m-strips, m fastest -> A band L2-resident across n-tiles.
  int mtile, ntile;
  {
    const int L = blockIdx.y * gridDim.x + blockIdx.x;
    const int gy = gridDim.y;
    if ((gy & 7) == 0) {
      const int mpx = gy >> 3;
      const int xcd = L & 7;
      const int slot = L >> 3;
      mtile = xcd * mpx + (slot % mpx);
      ntile = slot / mpx;
    } else {
      mtile = blockIdx.y; ntile = blockIdx.x;
    }
  }
  const long tileM = (long)mtile * 128;
  const long tileN = (long)ntile * 256;

  // --- staging geometry (chunk swizzle: stored col (ch&3) holds logical col
  // ((ch&3)-(row>>1))&3 -> frag ds_read_b128 conflict-free). sA: 512 chunks
  // (2/thread), sB: 1024 chunks (4/thread). LDS dest = chunk*16 (linear).
  const bf16* gA[2]; int ldA[2];
#pragma unroll
  for (int i = 0; i < 2; ++i) {
    const int ch = tid + i * 256;
    const int row = ch >> 2;
    const int cl = ((ch & 3) - (row >> 1)) & 3;
    gA[i] = A + (tileM + row) * (long)K + cl * 8;
    ldA[i] = ch * 8;
  }
  const bf16* gB[4]; int ldB[4];
#pragma unroll
  for (int j = 0; j < 4; ++j) {
    const int ch = tid + j * 256;
    const int row = ch >> 2;
    const int cl = ((ch & 3) - (row >> 1)) & 3;
    gB[j] = B + (tileN + row) * (long)K + cl * 8;
    ldB[j] = ch * 8;
  }

  // --- fragment LDS offsets (logical (r,q) lives at r*32 + ((q+(r>>1))&3)*8)
  int offA[8], offB[4];
#pragma unroll
  for (int mi = 0; mi < 8; ++mi) {
    const int r = mi * 16 + m16;                 // full 128 rows of sA
    offA[mi] = r * 32 + (((q + (r >> 1)) & 3) << 3);
  }
#pragma unroll
  for (int ni = 0; ni < 4; ++ni) {
    const int r = w * 64 + ni * 16 + m16;        // this wave's 64-col slice
    offB[ni] = r * 32 + (((q + (r >> 1)) & 3) << 3);
  }

  f32x4 acc[8][4] = {};

  // stage tile 0 into buf0
#pragma unroll
  for (int i = 0; i < 2; ++i)
    __builtin_amdgcn_global_load_lds(AS1(gA[i]), AS3(&sA0[ldA[i]]), 16, 0, 0);
#pragma unroll
  for (int j = 0; j < 4; ++j)
    __builtin_amdgcn_global_load_lds(AS1(gB[j]), AS3(&sB0[ldB[j]]), 16, 0, 0);
  __syncthreads();

  const bf16 *cra = sA0, *crb = sB0;
  bf16 *nxa = sA1, *nxb = sB1;

  for (long k0 = 32; k0 < K; k0 += 32) {
    // prefetch tile k0 into the other buffer (no wait here)
#pragma unroll
    for (int i = 0; i < 2; ++i)
      __builtin_amdgcn_global_load_lds(AS1(gA[i] + k0), AS3(&nxa[ldA[i]]), 16, 0, 0);
#pragma unroll
    for (int j = 0; j < 4; ++j)
      __builtin_amdgcn_global_load_lds(AS1(gB[j] + k0), AS3(&nxb[ldB[j]]), 16, 0, 0);

    // compute current tile: 12 ds_read_b128, 32 MFMA
    bf16x8 bfr[4];
#pragma unroll
    for (int ni = 0; ni < 4; ++ni) bfr[ni] = *(const bf16x8*)&crb[offB[ni]];
#pragma unroll
    for (int mi = 0; mi < 8; ++mi) {
      const bf16x8 af = *(const bf16x8*)&cra[offA[mi]];
#pragma unroll
      for (int ni = 0; ni < 4; ++ni)
        acc[mi][ni] = __builtin_amdgcn_mfma_f32_16x16x32_bf16(af, bfr[ni],
                                                              acc[mi][ni], 0, 0, 0);
    }

    __syncthreads();  // drains prefetch after it had compute-time to land

    const bf16* ta = cra; cra = nxa; nxa = (bf16*)ta;
    const bf16* tb = crb; crb = nxb; nxb = (bf16*)tb;
  }

  // last tile
  {
    bf16x8 bfr[4];
#pragma unroll
    for (int ni = 0; ni < 4; ++ni) bfr[ni] = *(const bf16x8*)&crb[offB[ni]];
#pragma unroll
    for (int mi = 0; mi < 8; ++mi) {
      const bf16x8 af = *(const bf16x8*)&cra[offA[mi]];
#pragma unroll
      for (int ni = 0; ni < 4; ++ni)
        acc[mi][ni] = __builtin_amdgcn_mfma_f32_16x16x32_bf16(af, bfr[ni],
                                                              acc[mi][ni], 0, 0, 0);
    }
  }

  // epilogue: C/D layout col = lane&15, row = (lane>>4)*4 + reg (m89-verified)
  const long colBase = tileN + (long)w * 64 + m16;
  const long rowBase = tileM + q * 4;
#pragma unroll
  for (int mi = 0; mi < 8; ++mi) {
#pragma unroll
    for (int r = 0; r < 4; ++r) {
      const long row = rowBase + mi * 16 + r;
#pragma unroll
      for (int ni = 0; ni < 4; ++ni) {
        const long col = colBase + ni * 16;
        float v = acc[mi][ni][r];
        if (EPI == 0) {
          ((bf16*)out)[row * N + col] = (bf16)v;
        } else if (EPI == 1) {
          v += bias[col] + (float)resid[row * N + col];
          ((float*)out)[row * N + col] = v;
        } else {
          v += bias[col];
          v = v > 0.f ? 1.0507009873554805f * v
                      : 1.0507009873554805f * 1.6732632423543772f * (__expf(v) - 1.f);
          ((bf16*)out)[row * N + col] = (bf16)v;
        }
      }
    }
  }
}

// ---------------------------------------------------------------------------
extern "C" void kernel_launch(void* const* d_in, const int* in_sizes, int n_in,
                              void* d_out, int out_size, void* d_ws, size_t ws_size,
                              hipStream_t stream) {
  const float* patches   = (const float*)d_in[0];
  const float* in_weight = (const float*)d_in[1];
  const float* in_bias   = (const float*)d_in[2];
  const float* out_w     = (const float*)d_in[3];
  const float* out_b     = (const float*)d_in[4];
  const float* mlp_w1    = (const float*)d_in[5];
  const float* mlp_b1    = (const float*)d_in[6];
  const float* mlp_w2    = (const float*)d_in[7];
  const float* mlp_b2    = (const float*)d_in[8];
  const float* ln1_g     = (const float*)d_in[9];
  const float* ln1_b     = (const float*)d_in[10];
  const float* ln2_g     = (const float*)d_in[11];
  const float* ln2_b     = (const float*)d_in[12];

  char* ws = (char*)d_ws;
  const size_t MB = 1024 * 1024;
  bf16* Wc   = (bf16*)(ws + 0);
  bf16* w1b  = (bf16*)(ws + 2 * MB);
  bf16* w2b  = (bf16*)(ws + 8 * MB);
  bf16* owb  = (bf16*)(ws + 14 * MB);
  bf16* wvt  = (bf16*)(ws + 16 * MB);
  float* bc  = (float*)(ws + 18 * MB);
  bf16* X1   = (bf16*)(ws + 20 * MB);  // reused as X3
  bf16* X3   = (bf16*)(ws + 20 * MB);
  bf16* H    = (bf16*)(ws + 48 * MB);
  float* X2  = (float*)d_out;          // fp32 scratch inside d_out

  cast_kernel<<<(3072 * 768 / 4 + 255) / 256, 256, 0, stream>>>(mlp_w1, w1b, 3072 * 768 / 4);
  cast_kernel<<<(768 * 3072 / 4 + 255) / 256, 256, 0, stream>>>(mlp_w2, w2b, 768 * 3072 / 4);
  cast_kernel<<<(768 * 768 / 4 + 255) / 256, 256, 0, stream>>>(out_w, owb, 768 * 768 / 4);
  wvt_kernel<<<dim3(3, 768), 256, 0, stream>>>(in_weight, wvt);
  bias_combine_kernel<<<768, 64, 0, stream>>>(out_w, in_bias, out_b, bc);
  gemm_bt<0><<<dim3(3, 6), 256, 0, stream>>>(owb, wvt, nullptr, nullptr, Wc, 768, 768, 768);

  ln_kernel<<<N_ROWS, 256, 0, stream>>>(patches, ln1_g, ln1_b, X1);
  gemm_bt<1><<<dim3(3, 128), 256, 0, stream>>>(X1, Wc, bc, X1, X2, N_ROWS, 768, 768);
  ln_kernel<<<N_ROWS, 256, 0, stream>>>(X2, ln2_g, ln2_b, X3);
  gemm_bt<2><<<dim3(12, 128), 256, 0, stream>>>(X3, w1b, mlp_b1, nullptr, H, N_ROWS, 3072, 768);
  gemm_bt<1><<<dim3(3, 128), 256, 0, stream>>>(H, w2b, mlp_b2, X3, d_out, N_ROWS, 768, 3072);
}